// Round 22
// baseline (307.101 us; speedup 1.0000x reference)
//
#include <hip/hip_runtime.h>
#include <hip/hip_bf16.h>
#include <stdint.h>

typedef __attribute__((ext_vector_type(8))) short  short8;   // 8 x bf16 fragment
typedef __attribute__((ext_vector_type(4))) float  f32x4;

#define C_IN  128
#define O_CH  256
#define NH    5
#define TSIZE 2048
#define HWDIM 56
#define NPIX  3136        // 56*56
#define MTOT  100352      // 32*3136
#define KTOT  1152        // 128*9
#define ADIM  1161        // KTOT + 9
#define PADW  58
#define PPIX  3364        // 58*58
#define NHC   8           // global-hist copies
#define LBINS 192         // LDS hist bins per hash (spill path covers the rest)

static __device__ __forceinline__ unsigned short f2bf(float f) {
  unsigned int u = __float_as_uint(f);
  return (unsigned short)((u + 0x7fffu + ((u >> 16) & 1u)) >> 16);   // RNE
}

// async global->LDS, 16B per lane; LDS dest = wave-uniform base + lane*16
static __device__ __forceinline__ void gload16(const unsigned short* g, unsigned short* l) {
  __builtin_amdgcn_global_load_lds(
      (const __attribute__((address_space(1))) void*)g,
      (__attribute__((address_space(3))) void*)l, 16, 0, 0);
}

#define WAITV(n) asm volatile("s_waitcnt vmcnt(" #n ")" ::: "memory")
static __device__ __forceinline__ void barsync() {
  asm volatile("" ::: "memory");
  __builtin_amdgcn_s_barrier();
  __builtin_amdgcn_sched_barrier(0);
  asm volatile("" ::: "memory");
}

// ---- fused prep: packw [0,1152) | packa [1152,1175) | ghist0 [1175,1215) | ring | packx | norms ----
__global__ __launch_bounds__(256) void k_prep(const float* __restrict__ w,
    const float* __restrict__ a, const float* __restrict__ x,
    unsigned short* __restrict__ wpk, unsigned short* __restrict__ xpq,
    float* __restrict__ apk, int* __restrict__ ghist, double* __restrict__ ssbuf,
    int doPack, int doPackX, int qstride, int ringN) {
  int bid = blockIdx.x, t = threadIdx.x;
  if (bid < 1152) {
    if (!doPack) return;
    int idx = bid * 256 + t;                      // < 294912 exact
    int kt = idx >> 13; int rem = idx & 8191;     // 8192 = 256*32
    int o = rem >> 5; int cl = rem & 31;
    int kyx = kt >> 2, cq = kt & 3;
    wpk[idx] = f2bf(w[o * KTOT + (cq * 32 + cl) * 9 + kyx]);
  } else if (bid < 1175) {
    int i = (bid - 1152) * 256 + t;               // 128*45 = 5760
    if (i < C_IN * 45) {
      int c = i / 45, r = i - c * 45;             // r = h*9+k
      int h = r / 9, k = r - h * 9;
      apk[c * 48 + r] = a[h * ADIM + c * 9 + k];
    }
  } else if (bid < 1215) {
    int i = (bid - 1175) * 2048 + t;              // 40*2048 = 81920 = NHC*NH*TSIZE exact
    #pragma unroll
    for (int j = 0; j < 8; ++j) ghist[i + j * 256] = 0;
  } else if (bid < 1215 + ringN) {
    if (!doPack) return;
    int b2 = bid - 1215;                          // ring zero, quarter-split layout
    int cq = b2 & 3; int rest = b2 >> 2;
    int r = rest % PADW, bl = rest / PADW;
    unsigned short* row = xpq + ((size_t)cq * qstride + (size_t)bl * PPIX + (size_t)r * PADW) * 32;
    if (r == 0 || r == PADW - 1) {
      for (int i = t; i < PADW * 32; i += 256) row[i] = 0;
    } else {
      if (t < 32) row[t] = 0;                     // col 0
      else if (t < 64) row[57 * 32 + (t - 32)] = 0;  // col 57
    }
  } else if (bid < 1215 + ringN + 1792) {
    if (!doPackX) return;                         // full-batch packx (b0 = 0)
    int b3 = bid - 1215 - ringN;
    int bl = b3 / HWDIM; int y = b3 - bl * HWDIM;
    __shared__ unsigned short th[C_IN * 57];      // +1 pad on 56
    const float* xb = x + (size_t)(bl * C_IN) * NPIX + y * HWDIM;
    for (int i = t; i < C_IN * HWDIM; i += 256) {
      int c = i / HWDIM; int xx = i - c * HWDIM;
      th[c * 57 + xx] = f2bf(xb[c * NPIX + xx]);
    }
    __syncthreads();
    size_t pbase = (size_t)bl * PPIX + (size_t)(y + 1) * PADW + 1;
    for (int i = t; i < C_IN * HWDIM; i += 256) {
      int xx = i >> 7; int c = i & 127;
      xpq[((size_t)(c >> 5) * qstride + pbase + xx) * 32 + (c & 31)] = th[c * 57 + xx];
    }
  } else {
    int o = bid - 1215 - ringN - 1792;            // 0..255 : w row sum-of-squares (fp64)
    __shared__ double red[256];
    double ss = 0.;
    for (int i = t; i < KTOT; i += 256) { double v = (double)w[o * KTOT + i]; ss += v * v; }
    red[t] = ss;
    __syncthreads();
    for (int s = 128; s; s >>= 1) { if (t < s) red[t] += red[t + s]; __syncthreads(); }
    if (t == 0) ssbuf[o] = red[0];
  }
}

// ---------------- table build (fp64 decision path — verified R3..R21) ----------------
__global__ __launch_bounds__(256) void k_table(const float* __restrict__ w,
    const float* __restrict__ a, const float* __restrict__ b_unit,
    const double* __restrict__ ssbuf, int* __restrict__ kbucket) {
  int o = blockIdx.x, t = threadIdx.x;
  __shared__ double red[256];
  __shared__ double r6[6][256];
  red[t] = ssbuf[t];
  __syncthreads();
  for (int s = 128; s; s >>= 1) { if (t < s) red[t] = fmax(red[t], red[t + s]); __syncthreads(); }
  double scale = 0.99 / sqrt(red[0]);             // U / denom
  double pd0 = 0, pd1 = 0, pd2 = 0, pd3 = 0, pd4 = 0, ss2 = 0;
  for (int i = t; i < KTOT; i += 256) {
    double wv = scale * (double)w[o * KTOT + i];
    ss2 += wv * wv;
    pd0 += wv * (double)a[0 * ADIM + i];
    pd1 += wv * (double)a[1 * ADIM + i];
    pd2 += wv * (double)a[2 * ADIM + i];
    pd3 += wv * (double)a[3 * ADIM + i];
    pd4 += wv * (double)a[4 * ADIM + i];
  }
  r6[0][t] = ss2; r6[1][t] = pd0; r6[2][t] = pd1; r6[3][t] = pd2; r6[4][t] = pd3; r6[5][t] = pd4;
  __syncthreads();
  for (int s = 128; s; s >>= 1) {
    if (t < s) { for (int q = 0; q < 6; ++q) r6[q][t] += r6[q][t + s]; }
    __syncthreads();
  }
  if (t == 0) {
    double nrm = sqrt(r6[0][0]);
    double q = nrm;
    double dp[NH] = {0, 0, 0, 0, 0};
    for (int j = 0; j < 9; ++j) {
      q = q * q;                                   // nrm^2, nrm^4, ..., nrm^512
      #pragma unroll
      for (int h = 0; h < NH; ++h) dp[h] += q * (double)a[h * ADIM + KTOT + j];
    }
    #pragma unroll
    for (int h = 0; h < NH; ++h) {
      double tot = r6[1 + h][0] + dp[h] + (double)b_unit[h] * 4.0;
      int hv = (int)floor(tot * 0.25);
      int bk = hv % TSIZE; if (bk < 0) bk = -bk;
      kbucket[o * NH + h] = bk;
    }
  }
}

// ---------------- one-pass vote (verified R21): k_vote2 structure + wave-uniform apk loads ----------------
__global__ __launch_bounds__(256) void k_vote4(const float* __restrict__ x,
    const float* __restrict__ apk, const float* __restrict__ a,
    const float* __restrict__ b_unit, int* __restrict__ ghist) {
  __shared__ float red[4][NH][64];
  __shared__ int   lh[NH * LBINS];
  int t = threadIdx.x;
  int px = t & 63;
  int g = __builtin_amdgcn_readfirstlane(t >> 6);  // wave-uniform channel group -> s_loads
  for (int i = t; i < NH * LBINS; i += 256) lh[i] = 0;
  int p = blockIdx.x * 64 + px;                   // 1568*64 = 100352 exact
  int bb = p / NPIX; int rem = p - bb * NPIX;
  int y = rem / HWDIM; int xx = rem - y * HWDIM;
  bool x0 = xx > 0, x2 = xx < HWDIM - 1, y0 = y > 0, y2 = y < HWDIM - 1;
  const float* xb = x + ((size_t)bb * C_IN + g * 32) * NPIX + y * HWDIM + xx;
  const float* ap = apk + (g * 32) * 48;          // uniform base
  float acc[NH] = {0, 0, 0, 0, 0};
  for (int c = 0; c < 32; ++c) {
    const float* xc = xb + c * NPIX;
    float v0 = 0, v1 = 0, v2 = 0, v3 = 0, v5 = 0, v6 = 0, v7 = 0, v8 = 0;
    float v4 = xc[0];
    if (x0) v3 = xc[-1];
    if (x2) v5 = xc[1];
    if (y0) { v1 = xc[-HWDIM]; if (x0) v0 = xc[-HWDIM - 1]; if (x2) v2 = xc[-HWDIM + 1]; }
    if (y2) { v7 = xc[HWDIM];  if (x0) v6 = xc[HWDIM - 1];  if (x2) v8 = xc[HWDIM + 1]; }
    const float* ac = ap + c * 48;
    #pragma unroll
    for (int h = 0; h < NH; ++h) {
      const float* ah = ac + h * 9;               // apk values == a values; same FMA order as R5
      acc[h] += v0 * ah[0] + v1 * ah[1] + v2 * ah[2] + v3 * ah[3] + v4 * ah[4]
              + v5 * ah[5] + v6 * ah[6] + v7 * ah[7] + v8 * ah[8];
    }
  }
  #pragma unroll
  for (int h = 0; h < NH; ++h) red[g][h][px] = acc[h];
  __syncthreads();
  int* gh = ghist + (blockIdx.x & (NHC - 1)) * NH * TSIZE;
  if (g == 0) {                                   // threads 0..63 finalize their pixel
    #pragma unroll
    for (int h = 0; h < NH; ++h) {
      float s = red[0][h][px] + red[1][h][px] + red[2][h][px] + red[3][h][px];
      const float* ah = a + h * ADIM + KTOT;      // appended 0.5 channel (zero pad ring)
      float e = ah[4];
      if (x0) e += ah[3];
      if (x2) e += ah[5];
      if (y0) { e += ah[1]; if (x0) e += ah[0]; if (x2) e += ah[2]; }
      if (y2) { e += ah[7]; if (x0) e += ah[6]; if (x2) e += ah[8]; }
      s += 0.5f * e;
      int hv = (int)floorf((s + b_unit[h] * 4.0f) * 0.25f);
      int bk = hv % TSIZE; if (bk < 0) bk = -bk;
      if (bk < LBINS) atomicAdd(&lh[h * LBINS + bk], 1);
      else            atomicAdd(&gh[h * TSIZE + bk], 1);     // rare spill
    }
  }
  __syncthreads();
  for (int i = t; i < NH * LBINS; i += 256) {
    int v = lh[i];
    if (v) { int h = i / LBINS, bk = i - h * LBINS; atomicAdd(&gh[h * TSIZE + bk], v); }
  }
}

// ---------------- argmax + mask (verified R9..R21) ----------------
__global__ __launch_bounds__(256) void k_argmax(const int* __restrict__ ghist, int* __restrict__ sel) {
  int h = blockIdx.x;                             // 0..4
  int t = threadIdx.x;
  __shared__ int rc[256], ri[256];
  int bc = -1, bi = 0;
  for (int i = t; i < TSIZE; i += 256) {          // ascending i + strict '>' = first-max
    int c = 0;
    #pragma unroll
    for (int k = 0; k < NHC; ++k) c += ghist[(k * NH + h) * TSIZE + i];
    if (c > bc) { bc = c; bi = i; }
  }
  rc[t] = bc; ri[t] = bi;
  __syncthreads();
  for (int s = 128; s; s >>= 1) {
    if (t < s) {
      if (rc[t + s] > rc[t] || (rc[t + s] == rc[t] && ri[t + s] < ri[t])) {
        rc[t] = rc[t + s]; ri[t] = ri[t + s];
      }
    }
    __syncthreads();
  }
  if (t == 0) sel[h] = ri[0];
}

__global__ __launch_bounds__(256) void k_mask(const int* __restrict__ sel,
    const int* __restrict__ kbucket, float* __restrict__ mscale) {
  int t = threadIdx.x;
  __shared__ int cnt[256], ssel[NH];
  if (t < NH) ssel[t] = sel[t];
  __syncthreads();
  bool act = false;
  #pragma unroll
  for (int i = 0; i < NH; ++i) {
    int kb = kbucket[t * NH + i];
    #pragma unroll
    for (int j = 0; j < NH; ++j) act = act || (kb == ssel[j]);
  }
  cnt[t] = act ? 1 : 0;
  __syncthreads();
  for (int s = 128; s; s >>= 1) { if (t < s) cnt[t] += cnt[t + s]; __syncthreads(); }
  int n = cnt[0];
  bool a2 = act;
  if (n == 0) { a2 = true; n = 256; }             // fallback: all active
  mscale[t] = a2 ? 256.0f / (float)n : 0.0f;
}

// ---------------- x pack (slice fallback path only, NB<32) ----------------
__global__ __launch_bounds__(256) void k_packx1(const float* __restrict__ x, int b0,
                                                unsigned short* __restrict__ xpq, int qstride) {
  int bl = blockIdx.x / HWDIM; int y = blockIdx.x - bl * HWDIM;   // bl = slice-local batch
  int t = threadIdx.x;
  __shared__ unsigned short th[C_IN * 57];        // +1 pad on 56
  const float* xb = x + (size_t)((b0 + bl) * C_IN) * NPIX + y * HWDIM;
  for (int i = t; i < C_IN * HWDIM; i += 256) {
    int c = i / HWDIM; int xx = i - c * HWDIM;
    th[c * 57 + xx] = f2bf(xb[c * NPIX + xx]);
  }
  __syncthreads();
  size_t pbase = (size_t)bl * PPIX + (size_t)(y + 1) * PADW + 1;
  for (int i = t; i < C_IN * HWDIM; i += 256) {
    int xx = i >> 7; int c = i & 127;
    xpq[((size_t)(c >> 5) * qstride + pbase + xx) * 32 + (c & 31)] = th[c * 57 + xx];
  }
}

// ---------------- main conv: R21-exact, launch_bounds(256,5) -> 5 blocks/CU ----------------
__global__ __launch_bounds__(256, 5) void k_gemmA(
    const unsigned short* __restrict__ xpq, const unsigned short* __restrict__ wpk,
    const float* __restrict__ bias, const float* __restrict__ mscale,
    float* __restrict__ out, int b0, int qstride) {
  // bijective XCD swizzle (m204)
  int nwg = gridDim.x, orig = blockIdx.x;
  int q = nwg >> 3, r = nwg & 7, xcd = orig & 7, loc = orig >> 3;
  int bid = (xcd < r ? xcd * (q + 1) : r * (q + 1) + (xcd - r) * q) + loc;
  int mtile = bid >> 1;                           // M-tiles of 128 pixels (slice-local)
  int ntile = bid & 1;                            // 2 N-tiles of 128 out-channels
  int tid = threadIdx.x;
  int lane = tid & 63, wv = tid >> 6;
  int wr = wv >> 1, wc = wv & 1;                  // 2x2 wave grid, 64x64 each
  __shared__ __attribute__((aligned(16))) unsigned short As[2][128 * 32];  // 16 KB
  __shared__ __attribute__((aligned(16))) unsigned short Bs[2][128 * 32];  // 16 KB

  // staging map (3-bit swizzle, conflict-free per R18): thread t fills chunks t, 256+t
  int pixS[2], chS[2], srcB[2], ldst[2];
  #pragma unroll
  for (int j = 0; j < 2; ++j) {
    int L = j * 256 + tid;                        // 0..511 : linear 16B chunk
    int lrow = L >> 3, pc = L & 7;
    int c3 = pc ^ (lrow & 7);                     // inverse swizzle
    int mrow = (lrow << 1) | (c3 >> 2);
    int ch = c3 & 3;
    int mg = mtile * 128 + mrow;
    int bb = (unsigned)mg / NPIX; int rem = mg - bb * NPIX;
    int y = (unsigned)rem / HWDIM; int xx = rem - y * HWDIM;
    pixS[j] = bb * PPIX + y * PADW + xx;
    chS[j]  = ch * 8;                             // element offset within 32-elem K seg
    srcB[j] = (ntile * 128 + mrow) * 32 + ch * 8; // + kt*8192 at use
    ldst[j] = L * 8;                              // LDS element offset (L*16 bytes)
  }

  f32x4 acc[4][4];
  #pragma unroll
  for (int mi = 0; mi < 4; ++mi)
    #pragma unroll
    for (int ni = 0; ni < 4; ++ni) acc[mi][ni] = (f32x4){0.f, 0.f, 0.f, 0.f};

  // read map (3-bit swizzle)
  int ar = lane & 15, hi = lane >> 4;
  int arh = ar >> 1;
  int pcr8 = (((ar & 1) << 2 | hi) ^ arh) << 3;   // swizzled chunk * 8 elements
  int rbA = (wr * 32 + arh) * 64 + pcr8;          // + mi*512 per frag
  int rbB = (wc * 32 + arh) * 64 + pcr8;          // + ni*512 per frag

  // prologue: stage tile 0 (tap 0, chan-quarter 0)
  #pragma unroll
  for (int j = 0; j < 2; ++j) {
    gload16(xpq + (size_t)pixS[j] * 32 + chS[j], &As[0][ldst[j]]);
    gload16(wpk + srcB[j], &Bs[0][ldst[j]]);
  }

  for (int kt = 0; kt < 36; ++kt) {               // 36 K-tiles of 32 (tap = kt>>2, cq = kt&3)
    int buf = kt & 1;
    if (kt < 35) {                                // stage kt+1 into other buffer
      int st = kt + 1, sb = st & 1, stap = st >> 2;
      int ky = stap / 3, kx = stap - ky * 3;
      size_t qoff = (size_t)(st & 3) * qstride + (ky * PADW + kx);
      #pragma unroll
      for (int j = 0; j < 2; ++j) {
        gload16(xpq + (qoff + pixS[j]) * 32 + chS[j], &As[sb][ldst[j]]);
        gload16(wpk + st * 8192 + srcB[j], &Bs[sb][ldst[j]]);
      }
      WAITV(4);                                   // tile kt retired; kt+1 stays in flight
    } else {
      WAITV(0);
    }
    barsync();
    short8 af[4], bf[4];
    #pragma unroll
    for (int mi = 0; mi < 4; ++mi) af[mi] = *(const short8*)&As[buf][rbA + mi * 512];
    #pragma unroll
    for (int ni = 0; ni < 4; ++ni) bf[ni] = *(const short8*)&Bs[buf][rbB + ni * 512];
    __builtin_amdgcn_s_setprio(1);                // T5 (kept: cost-free)
    #pragma unroll
    for (int mi = 0; mi < 4; ++mi)
      #pragma unroll
      for (int ni = 0; ni < 4; ++ni)
        acc[mi][ni] = __builtin_amdgcn_mfma_f32_16x16x32_bf16(af[mi], bf[ni], acc[mi][ni], 0, 0, 0);
    __builtin_amdgcn_s_setprio(0);
    barsync();
  }

  // epilogue: D col = lane&15 (o), row = (lane>>4)*4+j (m)  [m89-verified layout]
  int r4 = hi << 2;
  int cn = ar;
  #pragma unroll
  for (int ni = 0; ni < 4; ++ni) {
    int o = ntile * 128 + wc * 64 + ni * 16 + cn;
    float ms = mscale[o], bi = bias[o];
    #pragma unroll
    for (int mi = 0; mi < 4; ++mi) {
      int mg = mtile * 128 + wr * 64 + mi * 16 + r4;
      int bb = (unsigned)mg / NPIX; int pix = mg - bb * NPIX;   // mg%4==0, NPIX%4==0
      f32x4 v;
      #pragma unroll
      for (int j = 0; j < 4; ++j) v[j] = (acc[mi][ni][j] + bi) * ms;
      *(f32x4*)(out + (size_t)(((b0 + bb) << 8) + o) * NPIX + pix) = v;
    }
  }
}

// ---------------- fallback value path (R3-verified): fp32 direct conv ----------------
__global__ __launch_bounds__(256) void k_dconv(const float* __restrict__ x,
    const float* __restrict__ w, const float* __restrict__ bias,
    const float* __restrict__ mscale, float* __restrict__ out) {
  int bid = blockIdx.x;
  int yq = bid % 14; int rem = bid / 14;
  int o = rem & 255; int b = rem >> 8;
  __shared__ float wsm[KTOT];
  for (int i = threadIdx.x; i < KTOT; i += 256) wsm[i] = w[o * KTOT + i];
  __syncthreads();
  int t = threadIdx.x;
  if (t >= 224) return;
  int y = yq * 4 + t / HWDIM;
  int xx = t % HWDIM;
  const float* xb = x + (size_t)b * C_IN * NPIX + y * HWDIM + xx;
  float acc = 0.f;
  bool y0 = y > 0, y2 = y < HWDIM - 1, x0 = xx > 0, x2 = xx < HWDIM - 1;
  for (int c = 0; c < C_IN; ++c) {
    const float* xc = xb + c * NPIX;
    const float* wc9 = wsm + c * 9;
    float s = xc[0] * wc9[4];
    if (x0) s += xc[-1] * wc9[3];
    if (x2) s += xc[1] * wc9[5];
    if (y0) { s += xc[-HWDIM] * wc9[1]; if (x0) s += xc[-HWDIM - 1] * wc9[0]; if (x2) s += xc[-HWDIM + 1] * wc9[2]; }
    if (y2) { s += xc[HWDIM] * wc9[7];  if (x0) s += xc[HWDIM - 1] * wc9[6];  if (x2) s += xc[HWDIM + 1] * wc9[8]; }
    acc += s;
  }
  out[((size_t)b * O_CH + o) * NPIX + y * HWDIM + xx] = (acc + bias[o]) * mscale[o];
}

extern "C" void kernel_launch(void* const* d_in, const int* in_sizes, int n_in,
                              void* d_out, int out_size, void* d_ws, size_t ws_size,
                              hipStream_t stream) {
  const float* x      = (const float*)d_in[0];
  const float* w      = (const float*)d_in[1];
  const float* bias   = (const float*)d_in[2];
  const float* a      = (const float*)d_in[3];
  const float* b_unit = (const float*)d_in[4];
  float* out = (float*)d_out;
  char* ws = (char*)d_ws;

  // small fixed region (bytes)
  int*    ghist   = (int*)   (ws);                // NHC*5*2048*4 = 327,680
  double* ssbuf   = (double*)(ws + 327680);       //  2,048 -> 329,728
  int*    kbucket = (int*)   (ws + 329728);       //  5,120 -> 334,848
  float*  mscale  = (float*) (ws + 334848);       //  1,024 -> 335,872
  float*  apk     = (float*) (ws + 335872);       // 24,576 -> 360,448
  int*    sel     = (int*)   (ws + 360448);       //     64 -> 360,512
  const size_t SMALL = 360512;

  const size_t GBASE = SMALL;                     // one-pass vote: no pdot
  const size_t WPT = 589824;                      // 36*256*32*2
  const size_t XPB = 861184;                      // 3364*128*2 per batch
  int NB = 0;
  for (int nb = 32; nb >= 2; nb -= 2)
    if (GBASE + WPT + (size_t)nb * XPB <= ws_size) { NB = nb; break; }
  int qstride = NB * PPIX;                        // pixels per channel-quarter plane
  int full = (NB == 32) ? 1 : 0;                  // full-batch packx folded into prep

  unsigned short* wpk = (unsigned short*)(ws + GBASE);
  unsigned short* xpq = (unsigned short*)(ws + GBASE + WPT);

  // fused prep: packw | packa | ghist zero | pad ring | (full) packx | norms
  int ringN = NB * PADW * 4;
  k_prep<<<1215 + ringN + 1792 + 256, 256, 0, stream>>>(
      w, a, x, wpk, xpq, apk, ghist, ssbuf, NB > 0 ? 1 : 0, full, qstride, ringN);

  k_table <<<256, 256, 0, stream>>>(w, a, b_unit, ssbuf, kbucket);
  k_vote4 <<<1568, 256, 0, stream>>>(x, apk, a, b_unit, ghist);
  k_argmax<<<NH, 256, 0, stream>>>(ghist, sel);
  k_mask  <<<1, 256, 0, stream>>>(sel, kbucket, mscale);

  if (NB == 0) {                                  // ws too small: verified fallback
    k_dconv<<<32 * 256 * 14, 256, 0, stream>>>(x, w, bias, mscale, out);
    return;
  }

  for (int b0 = 0; b0 < 32; b0 += NB) {
    int nb = NB < (32 - b0) ? NB : (32 - b0);     // even (NB even, 32 even)
    if (!full) k_packx1<<<nb * HWDIM, 256, 0, stream>>>(x, b0, xpq, qstride);
    int mtiles = nb * NPIX / 128;                 // nb even -> exact
    k_gemmA<<<mtiles * 2, 256, 0, stream>>>(xpq, wpk, bias, mscale, out, b0, qstride);
  }
}

// Round 23
// 153.865 us; speedup vs baseline: 1.9959x; 1.9959x over previous
//
#include <hip/hip_runtime.h>
#include <hip/hip_bf16.h>
#include <stdint.h>

typedef __attribute__((ext_vector_type(8))) short  short8;   // 8 x bf16 fragment
typedef __attribute__((ext_vector_type(4))) float  f32x4;

#define C_IN  128
#define O_CH  256
#define NH    5
#define TSIZE 2048
#define HWDIM 56
#define NPIX  3136        // 56*56
#define MTOT  100352      // 32*3136
#define KTOT  1152        // 128*9
#define ADIM  1161        // KTOT + 9
#define PADW  58
#define PPIX  3364        // 58*58
#define NHC   8           // global-hist copies
#define LBINS 192         // LDS hist bins per hash (spill path covers the rest)

static __device__ __forceinline__ unsigned short f2bf(float f) {
  unsigned int u = __float_as_uint(f);
  return (unsigned short)((u + 0x7fffu + ((u >> 16) & 1u)) >> 16);   // RNE
}

// async global->LDS, 16B per lane; LDS dest = wave-uniform base + lane*16
static __device__ __forceinline__ void gload16(const unsigned short* g, unsigned short* l) {
  __builtin_amdgcn_global_load_lds(
      (const __attribute__((address_space(1))) void*)g,
      (__attribute__((address_space(3))) void*)l, 16, 0, 0);
}

#define WAITV(n) asm volatile("s_waitcnt vmcnt(" #n ")" ::: "memory")
static __device__ __forceinline__ void barsync() {
  asm volatile("" ::: "memory");
  __builtin_amdgcn_s_barrier();
  __builtin_amdgcn_sched_barrier(0);
  asm volatile("" ::: "memory");
}

// ---- fused prep: packw [0,1152) | packa [1152,1175) | ghist0 [1175,1215) | ring | packx | norms ----
__global__ __launch_bounds__(256) void k_prep(const float* __restrict__ w,
    const float* __restrict__ a, const float* __restrict__ x,
    unsigned short* __restrict__ wpk, unsigned short* __restrict__ xpq,
    float* __restrict__ apk, int* __restrict__ ghist, double* __restrict__ ssbuf,
    int doPack, int doPackX, int qstride, int ringN) {
  int bid = blockIdx.x, t = threadIdx.x;
  if (bid < 1152) {
    if (!doPack) return;
    int idx = bid * 256 + t;                      // < 294912 exact
    int kt = idx >> 13; int rem = idx & 8191;     // 8192 = 256*32
    int o = rem >> 5; int cl = rem & 31;
    int kyx = kt >> 2, cq = kt & 3;
    wpk[idx] = f2bf(w[o * KTOT + (cq * 32 + cl) * 9 + kyx]);
  } else if (bid < 1175) {
    int i = (bid - 1152) * 256 + t;               // 128*45 = 5760
    if (i < C_IN * 45) {
      int c = i / 45, r = i - c * 45;             // r = h*9+k
      int h = r / 9, k = r - h * 9;
      apk[c * 48 + r] = a[h * ADIM + c * 9 + k];
    }
  } else if (bid < 1215) {
    int i = (bid - 1175) * 2048 + t;              // 40*2048 = 81920 = NHC*NH*TSIZE exact
    #pragma unroll
    for (int j = 0; j < 8; ++j) ghist[i + j * 256] = 0;
  } else if (bid < 1215 + ringN) {
    if (!doPack) return;
    int b2 = bid - 1215;                          // ring zero, quarter-split layout
    int cq = b2 & 3; int rest = b2 >> 2;
    int r = rest % PADW, bl = rest / PADW;
    unsigned short* row = xpq + ((size_t)cq * qstride + (size_t)bl * PPIX + (size_t)r * PADW) * 32;
    if (r == 0 || r == PADW - 1) {
      for (int i = t; i < PADW * 32; i += 256) row[i] = 0;
    } else {
      if (t < 32) row[t] = 0;                     // col 0
      else if (t < 64) row[57 * 32 + (t - 32)] = 0;  // col 57
    }
  } else if (bid < 1215 + ringN + 1792) {
    if (!doPackX) return;                         // full-batch packx (b0 = 0)
    int b3 = bid - 1215 - ringN;
    int bl = b3 / HWDIM; int y = b3 - bl * HWDIM;
    __shared__ unsigned short th[C_IN * 57];      // +1 pad on 56
    const float* xb = x + (size_t)(bl * C_IN) * NPIX + y * HWDIM;
    for (int i = t; i < C_IN * HWDIM; i += 256) {
      int c = i / HWDIM; int xx = i - c * HWDIM;
      th[c * 57 + xx] = f2bf(xb[c * NPIX + xx]);
    }
    __syncthreads();
    size_t pbase = (size_t)bl * PPIX + (size_t)(y + 1) * PADW + 1;
    for (int i = t; i < C_IN * HWDIM; i += 256) {
      int xx = i >> 7; int c = i & 127;
      xpq[((size_t)(c >> 5) * qstride + pbase + xx) * 32 + (c & 31)] = th[c * 57 + xx];
    }
  } else {
    int o = bid - 1215 - ringN - 1792;            // 0..255 : w row sum-of-squares (fp64)
    __shared__ double red[256];
    double ss = 0.;
    for (int i = t; i < KTOT; i += 256) { double v = (double)w[o * KTOT + i]; ss += v * v; }
    red[t] = ss;
    __syncthreads();
    for (int s = 128; s; s >>= 1) { if (t < s) red[t] += red[t + s]; __syncthreads(); }
    if (t == 0) ssbuf[o] = red[0];
  }
}

// ---------------- table build (fp64 decision path — verified R3..R22) ----------------
__global__ __launch_bounds__(256) void k_table(const float* __restrict__ w,
    const float* __restrict__ a, const float* __restrict__ b_unit,
    const double* __restrict__ ssbuf, int* __restrict__ kbucket) {
  int o = blockIdx.x, t = threadIdx.x;
  __shared__ double red[256];
  __shared__ double r6[6][256];
  red[t] = ssbuf[t];
  __syncthreads();
  for (int s = 128; s; s >>= 1) { if (t < s) red[t] = fmax(red[t], red[t + s]); __syncthreads(); }
  double scale = 0.99 / sqrt(red[0]);             // U / denom
  double pd0 = 0, pd1 = 0, pd2 = 0, pd3 = 0, pd4 = 0, ss2 = 0;
  for (int i = t; i < KTOT; i += 256) {
    double wv = scale * (double)w[o * KTOT + i];
    ss2 += wv * wv;
    pd0 += wv * (double)a[0 * ADIM + i];
    pd1 += wv * (double)a[1 * ADIM + i];
    pd2 += wv * (double)a[2 * ADIM + i];
    pd3 += wv * (double)a[3 * ADIM + i];
    pd4 += wv * (double)a[4 * ADIM + i];
  }
  r6[0][t] = ss2; r6[1][t] = pd0; r6[2][t] = pd1; r6[3][t] = pd2; r6[4][t] = pd3; r6[5][t] = pd4;
  __syncthreads();
  for (int s = 128; s; s >>= 1) {
    if (t < s) { for (int q = 0; q < 6; ++q) r6[q][t] += r6[q][t + s]; }
    __syncthreads();
  }
  if (t == 0) {
    double nrm = sqrt(r6[0][0]);
    double q = nrm;
    double dp[NH] = {0, 0, 0, 0, 0};
    for (int j = 0; j < 9; ++j) {
      q = q * q;                                   // nrm^2, nrm^4, ..., nrm^512
      #pragma unroll
      for (int h = 0; h < NH; ++h) dp[h] += q * (double)a[h * ADIM + KTOT + j];
    }
    #pragma unroll
    for (int h = 0; h < NH; ++h) {
      double tot = r6[1 + h][0] + dp[h] + (double)b_unit[h] * 4.0;
      int hv = (int)floor(tot * 0.25);
      int bk = hv % TSIZE; if (bk < 0) bk = -bk;
      kbucket[o * NH + h] = bk;
    }
  }
}

// ---------------- one-pass vote (verified R21): k_vote2 structure + wave-uniform apk loads ----------------
__global__ __launch_bounds__(256) void k_vote4(const float* __restrict__ x,
    const float* __restrict__ apk, const float* __restrict__ a,
    const float* __restrict__ b_unit, int* __restrict__ ghist) {
  __shared__ float red[4][NH][64];
  __shared__ int   lh[NH * LBINS];
  int t = threadIdx.x;
  int px = t & 63;
  int g = __builtin_amdgcn_readfirstlane(t >> 6);  // wave-uniform channel group -> s_loads
  for (int i = t; i < NH * LBINS; i += 256) lh[i] = 0;
  int p = blockIdx.x * 64 + px;                   // 1568*64 = 100352 exact
  int bb = p / NPIX; int rem = p - bb * NPIX;
  int y = rem / HWDIM; int xx = rem - y * HWDIM;
  bool x0 = xx > 0, x2 = xx < HWDIM - 1, y0 = y > 0, y2 = y < HWDIM - 1;
  const float* xb = x + ((size_t)bb * C_IN + g * 32) * NPIX + y * HWDIM + xx;
  const float* ap = apk + (g * 32) * 48;          // uniform base
  float acc[NH] = {0, 0, 0, 0, 0};
  for (int c = 0; c < 32; ++c) {
    const float* xc = xb + c * NPIX;
    float v0 = 0, v1 = 0, v2 = 0, v3 = 0, v5 = 0, v6 = 0, v7 = 0, v8 = 0;
    float v4 = xc[0];
    if (x0) v3 = xc[-1];
    if (x2) v5 = xc[1];
    if (y0) { v1 = xc[-HWDIM]; if (x0) v0 = xc[-HWDIM - 1]; if (x2) v2 = xc[-HWDIM + 1]; }
    if (y2) { v7 = xc[HWDIM];  if (x0) v6 = xc[HWDIM - 1];  if (x2) v8 = xc[HWDIM + 1]; }
    const float* ac = ap + c * 48;
    #pragma unroll
    for (int h = 0; h < NH; ++h) {
      const float* ah = ac + h * 9;               // apk values == a values; same FMA order as R5
      acc[h] += v0 * ah[0] + v1 * ah[1] + v2 * ah[2] + v3 * ah[3] + v4 * ah[4]
              + v5 * ah[5] + v6 * ah[6] + v7 * ah[7] + v8 * ah[8];
    }
  }
  #pragma unroll
  for (int h = 0; h < NH; ++h) red[g][h][px] = acc[h];
  __syncthreads();
  int* gh = ghist + (blockIdx.x & (NHC - 1)) * NH * TSIZE;
  if (g == 0) {                                   // threads 0..63 finalize their pixel
    #pragma unroll
    for (int h = 0; h < NH; ++h) {
      float s = red[0][h][px] + red[1][h][px] + red[2][h][px] + red[3][h][px];
      const float* ah = a + h * ADIM + KTOT;      // appended 0.5 channel (zero pad ring)
      float e = ah[4];
      if (x0) e += ah[3];
      if (x2) e += ah[5];
      if (y0) { e += ah[1]; if (x0) e += ah[0]; if (x2) e += ah[2]; }
      if (y2) { e += ah[7]; if (x0) e += ah[6]; if (x2) e += ah[8]; }
      s += 0.5f * e;
      int hv = (int)floorf((s + b_unit[h] * 4.0f) * 0.25f);
      int bk = hv % TSIZE; if (bk < 0) bk = -bk;
      if (bk < LBINS) atomicAdd(&lh[h * LBINS + bk], 1);
      else            atomicAdd(&gh[h * TSIZE + bk], 1);     // rare spill
    }
  }
  __syncthreads();
  for (int i = t; i < NH * LBINS; i += 256) {
    int v = lh[i];
    if (v) { int h = i / LBINS, bk = i - h * LBINS; atomicAdd(&gh[h * TSIZE + bk], v); }
  }
}

// ---------------- argmax + mask (verified R9..R22) ----------------
__global__ __launch_bounds__(256) void k_argmax(const int* __restrict__ ghist, int* __restrict__ sel) {
  int h = blockIdx.x;                             // 0..4
  int t = threadIdx.x;
  __shared__ int rc[256], ri[256];
  int bc = -1, bi = 0;
  for (int i = t; i < TSIZE; i += 256) {          // ascending i + strict '>' = first-max
    int c = 0;
    #pragma unroll
    for (int k = 0; k < NHC; ++k) c += ghist[(k * NH + h) * TSIZE + i];
    if (c > bc) { bc = c; bi = i; }
  }
  rc[t] = bc; ri[t] = bi;
  __syncthreads();
  for (int s = 128; s; s >>= 1) {
    if (t < s) {
      if (rc[t + s] > rc[t] || (rc[t + s] == rc[t] && ri[t + s] < ri[t])) {
        rc[t] = rc[t + s]; ri[t] = ri[t + s];
      }
    }
    __syncthreads();
  }
  if (t == 0) sel[h] = ri[0];
}

__global__ __launch_bounds__(256) void k_mask(const int* __restrict__ sel,
    const int* __restrict__ kbucket, float* __restrict__ mscale) {
  int t = threadIdx.x;
  __shared__ int cnt[256], ssel[NH];
  if (t < NH) ssel[t] = sel[t];
  __syncthreads();
  bool act = false;
  #pragma unroll
  for (int i = 0; i < NH; ++i) {
    int kb = kbucket[t * NH + i];
    #pragma unroll
    for (int j = 0; j < NH; ++j) act = act || (kb == ssel[j]);
  }
  cnt[t] = act ? 1 : 0;
  __syncthreads();
  for (int s = 128; s; s >>= 1) { if (t < s) cnt[t] += cnt[t + s]; __syncthreads(); }
  int n = cnt[0];
  bool a2 = act;
  if (n == 0) { a2 = true; n = 256; }             // fallback: all active
  mscale[t] = a2 ? 256.0f / (float)n : 0.0f;
}

// ---------------- x pack (slice fallback path only, NB<32) ----------------
__global__ __launch_bounds__(256) void k_packx1(const float* __restrict__ x, int b0,
                                                unsigned short* __restrict__ xpq, int qstride) {
  int bl = blockIdx.x / HWDIM; int y = blockIdx.x - bl * HWDIM;   // bl = slice-local batch
  int t = threadIdx.x;
  __shared__ unsigned short th[C_IN * 57];        // +1 pad on 56
  const float* xb = x + (size_t)((b0 + bl) * C_IN) * NPIX + y * HWDIM;
  for (int i = t; i < C_IN * HWDIM; i += 256) {
    int c = i / HWDIM; int xx = i - c * HWDIM;
    th[c * 57 + xx] = f2bf(xb[c * NPIX + xx]);
  }
  __syncthreads();
  size_t pbase = (size_t)bl * PPIX + (size_t)(y + 1) * PADW + 1;
  for (int i = t; i < C_IN * HWDIM; i += 256) {
    int xx = i >> 7; int c = i & 127;
    xpq[((size_t)(c >> 5) * qstride + pbase + xx) * 32 + (c & 31)] = th[c * 57 + xx];
  }
}

// ---------------- main conv: R21-exact (128x128, BK=32, 2-buffer WAITV(4), 3-bit swizzle, 4 blk/CU) ----------------
__global__ __launch_bounds__(256, 4) void k_gemmA(
    const unsigned short* __restrict__ xpq, const unsigned short* __restrict__ wpk,
    const float* __restrict__ bias, const float* __restrict__ mscale,
    float* __restrict__ out, int b0, int qstride) {
  // bijective XCD swizzle (m204)
  int nwg = gridDim.x, orig = blockIdx.x;
  int q = nwg >> 3, r = nwg & 7, xcd = orig & 7, loc = orig >> 3;
  int bid = (xcd < r ? xcd * (q + 1) : r * (q + 1) + (xcd - r) * q) + loc;
  int mtile = bid >> 1;                           // M-tiles of 128 pixels (slice-local)
  int ntile = bid & 1;                            // 2 N-tiles of 128 out-channels
  int tid = threadIdx.x;
  int lane = tid & 63, wv = tid >> 6;
  int wr = wv >> 1, wc = wv & 1;                  // 2x2 wave grid, 64x64 each
  __shared__ __attribute__((aligned(16))) unsigned short As[2][128 * 32];  // 16 KB
  __shared__ __attribute__((aligned(16))) unsigned short Bs[2][128 * 32];  // 16 KB

  // staging map (3-bit swizzle, conflict-free per R18): thread t fills chunks t, 256+t
  int pixS[2], chS[2], srcB[2], ldst[2];
  #pragma unroll
  for (int j = 0; j < 2; ++j) {
    int L = j * 256 + tid;                        // 0..511 : linear 16B chunk
    int lrow = L >> 3, pc = L & 7;
    int c3 = pc ^ (lrow & 7);                     // inverse swizzle
    int mrow = (lrow << 1) | (c3 >> 2);
    int ch = c3 & 3;
    int mg = mtile * 128 + mrow;
    int bb = (unsigned)mg / NPIX; int rem = mg - bb * NPIX;
    int y = (unsigned)rem / HWDIM; int xx = rem - y * HWDIM;
    pixS[j] = bb * PPIX + y * PADW + xx;
    chS[j]  = ch * 8;                             // element offset within 32-elem K seg
    srcB[j] = (ntile * 128 + mrow) * 32 + ch * 8; // + kt*8192 at use
    ldst[j] = L * 8;                              // LDS element offset (L*16 bytes)
  }

  f32x4 acc[4][4];
  #pragma unroll
  for (int mi = 0; mi < 4; ++mi)
    #pragma unroll
    for (int ni = 0; ni < 4; ++ni) acc[mi][ni] = (f32x4){0.f, 0.f, 0.f, 0.f};

  // read map (3-bit swizzle)
  int ar = lane & 15, hi = lane >> 4;
  int arh = ar >> 1;
  int pcr8 = (((ar & 1) << 2 | hi) ^ arh) << 3;   // swizzled chunk * 8 elements
  int rbA = (wr * 32 + arh) * 64 + pcr8;          // + mi*512 per frag
  int rbB = (wc * 32 + arh) * 64 + pcr8;          // + ni*512 per frag

  // prologue: stage tile 0 (tap 0, chan-quarter 0)
  #pragma unroll
  for (int j = 0; j < 2; ++j) {
    gload16(xpq + (size_t)pixS[j] * 32 + chS[j], &As[0][ldst[j]]);
    gload16(wpk + srcB[j], &Bs[0][ldst[j]]);
  }

  for (int kt = 0; kt < 36; ++kt) {               // 36 K-tiles of 32 (tap = kt>>2, cq = kt&3)
    int buf = kt & 1;
    if (kt < 35) {                                // stage kt+1 into other buffer
      int st = kt + 1, sb = st & 1, stap = st >> 2;
      int ky = stap / 3, kx = stap - ky * 3;
      size_t qoff = (size_t)(st & 3) * qstride + (ky * PADW + kx);
      #pragma unroll
      for (int j = 0; j < 2; ++j) {
        gload16(xpq + (qoff + pixS[j]) * 32 + chS[j], &As[sb][ldst[j]]);
        gload16(wpk + st * 8192 + srcB[j], &Bs[sb][ldst[j]]);
      }
      WAITV(4);                                   // tile kt retired; kt+1 stays in flight
    } else {
      WAITV(0);
    }
    barsync();
    short8 af[4], bf[4];
    #pragma unroll
    for (int mi = 0; mi < 4; ++mi) af[mi] = *(const short8*)&As[buf][rbA + mi * 512];
    #pragma unroll
    for (int ni = 0; ni < 4; ++ni) bf[ni] = *(const short8*)&Bs[buf][rbB + ni * 512];
    __builtin_amdgcn_s_setprio(1);
    #pragma unroll
    for (int mi = 0; mi < 4; ++mi)
      #pragma unroll
      for (int ni = 0; ni < 4; ++ni)
        acc[mi][ni] = __builtin_amdgcn_mfma_f32_16x16x32_bf16(af[mi], bf[ni], acc[mi][ni], 0, 0, 0);
    __builtin_amdgcn_s_setprio(0);
    barsync();
  }

  // epilogue: D col = lane&15 (o), row = (lane>>4)*4+j (m)  [m89-verified layout]
  int r4 = hi << 2;
  int cn = ar;
  #pragma unroll
  for (int ni = 0; ni < 4; ++ni) {
    int o = ntile * 128 + wc * 64 + ni * 16 + cn;
    float ms = mscale[o], bi = bias[o];
    #pragma unroll
    for (int mi = 0; mi < 4; ++mi) {
      int mg = mtile * 128 + wr * 64 + mi * 16 + r4;
      int bb = (unsigned)mg / NPIX; int pix = mg - bb * NPIX;   // mg%4==0, NPIX%4==0
      f32x4 v;
      #pragma unroll
      for (int j = 0; j < 4; ++j) v[j] = (acc[mi][ni][j] + bi) * ms;
      *(f32x4*)(out + (size_t)(((b0 + bb) << 8) + o) * NPIX + pix) = v;
    }
  }
}

// ---------------- fallback value path (R3-verified): fp32 direct conv ----------------
__global__ __launch_bounds__(256) void k_dconv(const float* __restrict__ x,
    const float* __restrict__ w, const float* __restrict__ bias,
    const float* __restrict__ mscale, float* __restrict__ out) {
  int bid = blockIdx.x;
  int yq = bid % 14; int rem = bid / 14;
  int o = rem & 255; int b = rem >> 8;
  __shared__ float wsm[KTOT];
  for (int i = threadIdx.x; i < KTOT; i += 256) wsm[i] = w[o * KTOT + i];
  __syncthreads();
  int t = threadIdx.x;
  if (t >= 224) return;
  int y = yq * 4 + t / HWDIM;
  int xx = t % HWDIM;
  const float* xb = x + (size_t)b * C_IN * NPIX + y * HWDIM + xx;
  float acc = 0.f;
  bool y0 = y > 0, y2 = y < HWDIM - 1, x0 = xx > 0, x2 = xx < HWDIM - 1;
  for (int c = 0; c < C_IN; ++c) {
    const float* xc = xb + c * NPIX;
    const float* wc9 = wsm + c * 9;
    float s = xc[0] * wc9[4];
    if (x0) s += xc[-1] * wc9[3];
    if (x2) s += xc[1] * wc9[5];
    if (y0) { s += xc[-HWDIM] * wc9[1]; if (x0) s += xc[-HWDIM - 1] * wc9[0]; if (x2) s += xc[-HWDIM + 1] * wc9[2]; }
    if (y2) { s += xc[HWDIM] * wc9[7];  if (x0) s += xc[HWDIM - 1] * wc9[6];  if (x2) s += xc[HWDIM + 1] * wc9[8]; }
    acc += s;
  }
  out[((size_t)b * O_CH + o) * NPIX + y * HWDIM + xx] = (acc + bias[o]) * mscale[o];
}

extern "C" void kernel_launch(void* const* d_in, const int* in_sizes, int n_in,
                              void* d_out, int out_size, void* d_ws, size_t ws_size,
                              hipStream_t stream) {
  const float* x      = (const float*)d_in[0];
  const float* w      = (const float*)d_in[1];
  const float* bias   = (const float*)d_in[2];
  const float* a      = (const float*)d_in[3];
  const float* b_unit = (const float*)d_in[4];
  float* out = (float*)d_out;
  char* ws = (char*)d_ws;

  // small fixed region (bytes)
  int*    ghist   = (int*)   (ws);                // NHC*5*2048*4 = 327,680
  double* ssbuf   = (double*)(ws + 327680);       //  2,048 -> 329,728
  int*    kbucket = (int*)   (ws + 329728);       //  5,120 -> 334,848
  float*  mscale  = (float*) (ws + 334848);       //  1,024 -> 335,872
  float*  apk     = (float*) (ws + 335872);       // 24,576 -> 360,448
  int*    sel     = (int*)   (ws + 360448);       //     64 -> 360,512
  const size_t SMALL = 360512;

  const size_t GBASE = SMALL;                     // one-pass vote: no pdot
  const size_t WPT = 589824;                      // 36*256*32*2
  const size_t XPB = 861184;                      // 3364*128*2 per batch
  int NB = 0;
  for (int nb = 32; nb >= 2; nb -= 2)
    if (GBASE + WPT + (size_t)nb * XPB <= ws_size) { NB = nb; break; }
  int qstride = NB * PPIX;                        // pixels per channel-quarter plane
  int full = (NB == 32) ? 1 : 0;                  // full-batch packx folded into prep

  unsigned short* wpk = (unsigned short*)(ws + GBASE);
  unsigned short* xpq = (unsigned short*)(ws + GBASE + WPT);

  // fused prep: packw | packa | ghist zero | pad ring | (full) packx | norms
  int ringN = NB * PADW * 4;
  k_prep<<<1215 + ringN + 1792 + 256, 256, 0, stream>>>(
      w, a, x, wpk, xpq, apk, ghist, ssbuf, NB > 0 ? 1 : 0, full, qstride, ringN);

  k_table <<<256, 256, 0, stream>>>(w, a, b_unit, ssbuf, kbucket);
  k_vote4 <<<1568, 256, 0, stream>>>(x, apk, a, b_unit, ghist);
  k_argmax<<<NH, 256, 0, stream>>>(ghist, sel);
  k_mask  <<<1, 256, 0, stream>>>(sel, kbucket, mscale);

  if (NB == 0) {                                  // ws too small: verified fallback
    k_dconv<<<32 * 256 * 14, 256, 0, stream>>>(x, w, bias, mscale, out);
    return;
  }

  for (int b0 = 0; b0 < 32; b0 += NB) {
    int nb = NB < (32 - b0) ? NB : (32 - b0);     // even (NB even, 32 even)
    if (!full) k_packx1<<<nb * HWDIM, 256, 0, stream>>>(x, b0, xpq, qstride);
    int mtiles = nb * NPIX / 128;                 // nb even -> exact
    k_gemmA<<<mtiles * 2, 256, 0, stream>>>(xpq, wpk, bias, mscale, out, b0, qstride);
  }
}